// Round 5
// baseline (357.635 us; speedup 1.0000x reference)
//
#include <hip/hip_runtime.h>

#define N_NODES 50000
#define N_EDGES 800000
#define HD 128
#define NGRAPH 64
#define NOUT 8
#define SLOTS 64
#define EPB 2048     /* edges per chunk in fillx */

typedef __attribute__((ext_vector_type(8))) short bf8_t;
typedef __attribute__((ext_vector_type(4))) float f4_t;
typedef __attribute__((ext_vector_type(8))) unsigned short us8;

__device__ __forceinline__ unsigned short f2b(float f) {   // fp32 -> bf16 RNE
    unsigned u = __float_as_uint(f);
    u += 0x7fffu + ((u >> 16) & 1u);
    return (unsigned short)(u >> 16);
}
__device__ __forceinline__ float b2f(unsigned short h) {
    return __uint_as_float(((unsigned)h) << 16);
}

// ---------------- convert W (3 mats) + zero degc/sums/cnt ----------------
__global__ __launch_bounds__(256) void cvtw_k(const float* __restrict__ W0,
                                              const float* __restrict__ W1,
                                              const float* __restrict__ W2,
                                              unsigned short* __restrict__ WT,
                                              int* __restrict__ degc,
                                              float* __restrict__ sums,
                                              float* __restrict__ cnt) {
    int idx = blockIdx.x * 256 + threadIdx.x;
    if (idx < 3 * HD * HD) {
        int w = idx >> 14;
        int rem = idx & 16383;
        int n = rem >> 7;
        int k = rem & 127;
        const float* W = (w == 0) ? W0 : (w == 1) ? W1 : W2;
        WT[(size_t)w * HD * HD + n * HD + k] = f2b(W[k * HD + n]);
    }
    if (idx < N_NODES) degc[idx] = 0;
    if (idx < NGRAPH * HD) sums[idx] = 0.f;
    if (idx < NGRAPH) cnt[idx] = 0.f;
}

// ---------------- XCD-partitioned CSR build (proven round 4) ----------------
__global__ __launch_bounds__(256) void fillx_k(const int* __restrict__ src,
                                               const int* __restrict__ dst,
                                               int* __restrict__ degc,
                                               unsigned short* __restrict__ slots) {
    const int p = blockIdx.x & 7;
    const int c = blockIdx.x >> 3;
    const int e0 = c * EPB;
    int e1 = e0 + EPB; if (e1 > N_EDGES) e1 = N_EDGES;
    for (int e = e0 + threadIdx.x; e < e1; e += 256) {
        int d = dst[e];
        if (((d >> 4) & 7) == p) {
            int s = src[e];
            int pos = atomicAdd(&degc[d], 1);
            if (pos < SLOTS)
                slots[(size_t)d * SLOTS + pos] = (unsigned short)s;
        }
    }
}

// ---------------- layer-0 MFMA matmul (fp32 in, bf16 out, *dinv epilogue) ----------------
__global__ __launch_bounds__(256) void mm_f32in_k(const float* __restrict__ X,
                                                  const unsigned short* __restrict__ WT,
                                                  const int* __restrict__ degc,
                                                  unsigned short* __restrict__ Y) {
    const int lane = threadIdx.x & 63;
    const int wave = threadIdx.x >> 6;
    const int r = lane & 15;
    const int q = lane >> 4;
    const int row0 = blockIdx.x * 64 + wave * 16;
    int arow = row0 + r; if (arow >= N_NODES) arow = N_NODES - 1;

    f4_t acc[8];
#pragma unroll
    for (int n = 0; n < 8; ++n) acc[n] = (f4_t){0.f, 0.f, 0.f, 0.f};

#pragma unroll
    for (int kb = 0; kb < 4; ++kb) {
        f4_t fa = __builtin_nontemporal_load((const f4_t*)(X + (size_t)arow * HD + kb * 32 + q * 8));
        f4_t fb = __builtin_nontemporal_load((const f4_t*)(X + (size_t)arow * HD + kb * 32 + q * 8 + 4));
        bf8_t a;
        a[0] = (short)f2b(fa[0]); a[1] = (short)f2b(fa[1]);
        a[2] = (short)f2b(fa[2]); a[3] = (short)f2b(fa[3]);
        a[4] = (short)f2b(fb[0]); a[5] = (short)f2b(fb[1]);
        a[6] = (short)f2b(fb[2]); a[7] = (short)f2b(fb[3]);
#pragma unroll
        for (int n = 0; n < 8; ++n) {
            bf8_t b = *(const bf8_t*)(WT + (size_t)(n * 16 + r) * HD + kb * 32 + q * 8);
            acc[n] = __builtin_amdgcn_mfma_f32_16x16x32_bf16(a, b, acc[n], 0, 0, 0);
        }
    }
    const int orow = row0 + q * 4;
#pragma unroll
    for (int i = 0; i < 4; ++i) {
        int rr = orow + i;
        if (rr < N_NODES) {
            float dv = rsqrtf((float)degc[rr] + 1.0f);
#pragma unroll
            for (int n = 0; n < 8; ++n)
                Y[(size_t)rr * HD + n * 16 + r] = f2b(acc[n][i] * dv);
        }
    }
}

// ---------------- bf16-input MFMA matmul (S @ W, *dinv epilogue) ----------------
__global__ __launch_bounds__(256) void mm_bf_k(const unsigned short* __restrict__ S,
                                               const unsigned short* __restrict__ WT,
                                               const int* __restrict__ degc,
                                               unsigned short* __restrict__ Y) {
    const int lane = threadIdx.x & 63;
    const int wave = threadIdx.x >> 6;
    const int r = lane & 15;
    const int q = lane >> 4;
    const int row0 = blockIdx.x * 64 + wave * 16;
    int arow = row0 + r; if (arow >= N_NODES) arow = N_NODES - 1;

    f4_t acc[8];
#pragma unroll
    for (int n = 0; n < 8; ++n) acc[n] = (f4_t){0.f, 0.f, 0.f, 0.f};

#pragma unroll
    for (int kb = 0; kb < 4; ++kb) {
        bf8_t a = *(const bf8_t*)(S + (size_t)arow * HD + kb * 32 + q * 8);
#pragma unroll
        for (int n = 0; n < 8; ++n) {
            bf8_t b = *(const bf8_t*)(WT + (size_t)(n * 16 + r) * HD + kb * 32 + q * 8);
            acc[n] = __builtin_amdgcn_mfma_f32_16x16x32_bf16(a, b, acc[n], 0, 0, 0);
        }
    }
    const int orow = row0 + q * 4;
#pragma unroll
    for (int i = 0; i < 4; ++i) {
        int rr = orow + i;
        if (rr < N_NODES) {
            float dv = rsqrtf((float)degc[rr] + 1.0f);
#pragma unroll
            for (int n = 0; n < 8; ++n)
                Y[(size_t)rr * HD + n * 16 + r] = f2b(acc[n][i] * dv);
        }
    }
}

// ---------------- XCD col-sliced gather: S = relu?(di*(agg+self)+b) ----------------
// Block b: p=b&7 (~XCD), slice=p&3 (cols [slice*32, +32) = one 64B line/row),
// half=p>>2 (64-node half of a 128-node chunk), chunk=b>>3.
// XCD k only touches 64B-aligned slice k&3 of T: 12.8/4=3.2MB working set fits
// its 4MB L2 -> gather rows become L2 hits. slots/degc get NT loads (no
// intra-XCD reuse) to keep the slice cache pure. No LDS, no barrier.
// Correctness never depends on the block->XCD mapping.
__global__ __launch_bounds__(256) void gslice_k(const unsigned short* __restrict__ T,
                                                const int* __restrict__ degc,
                                                const unsigned short* __restrict__ slots,
                                                const float* __restrict__ bias,
                                                unsigned short* __restrict__ S,
                                                int relu) {
    const int p = blockIdx.x & 7;
    const int chunk = blockIdx.x >> 3;
    const int slice = p & 3;
    const int half = p >> 2;
    const int g = threadIdx.x >> 2;        // 64 nodes per block
    const int l = threadIdx.x & 3;         // 4 lanes x 8 cols = 32 cols
    const int i = chunk * 128 + half * 64 + g;
    if (i >= N_NODES) return;
    const int col = slice * 32 + l * 8;

    const int dg = __builtin_nontemporal_load(degc + i);
    int dc = dg; if (dc > SLOTS) dc = SLOTS;
    const float di = rsqrtf((float)dg + 1.0f);
    const unsigned short* sl = slots + (size_t)i * SLOTS;

    float a[8];
#pragma unroll
    for (int k = 0; k < 8; ++k) a[k] = 0.f;
    int e = 0;
    for (; e + 15 < dc; e += 16) {
        us8 i0 = __builtin_nontemporal_load((const us8*)(sl + e));
        us8 i1 = __builtin_nontemporal_load((const us8*)(sl + e + 8));
        us8 v[16];
#pragma unroll
        for (int u = 0; u < 8; ++u) v[u]     = *(const us8*)(T + (size_t)i0[u] * HD + col);
#pragma unroll
        for (int u = 0; u < 8; ++u) v[u + 8] = *(const us8*)(T + (size_t)i1[u] * HD + col);
#pragma unroll
        for (int u = 0; u < 16; ++u) {
#pragma unroll
            for (int k = 0; k < 8; ++k) a[k] += b2f(v[u][k]);
        }
    }
    if (e < dc) {   // masked 16-chunk: vector index loads, raw[0] as safe clamp
        us8 i0 = __builtin_nontemporal_load((const us8*)(sl + e));
        us8 i1 = __builtin_nontemporal_load((const us8*)(sl + e + 8));
        const unsigned short safe = i0[0];
        int s[16]; float m[16];
#pragma unroll
        for (int u = 0; u < 8; ++u) {
            m[u] = (e + u < dc) ? 1.f : 0.f;
            s[u] = (e + u < dc) ? i0[u] : safe;
        }
#pragma unroll
        for (int u = 0; u < 8; ++u) {
            m[u + 8] = (e + 8 + u < dc) ? 1.f : 0.f;
            s[u + 8] = (e + 8 + u < dc) ? i1[u] : safe;
        }
        us8 v[16];
#pragma unroll
        for (int u = 0; u < 16; ++u) v[u] = *(const us8*)(T + (size_t)s[u] * HD + col);
#pragma unroll
        for (int u = 0; u < 16; ++u) {
#pragma unroll
            for (int k = 0; k < 8; ++k) a[k] = fmaf(m[u], b2f(v[u][k]), a[k]);
        }
    }
    us8 tv = *(const us8*)(T + (size_t)i * HD + col);
    float4 bv0 = *(const float4*)(bias + col);
    float4 bv1 = *(const float4*)(bias + col + 4);
    float bb[8] = {bv0.x, bv0.y, bv0.z, bv0.w, bv1.x, bv1.y, bv1.z, bv1.w};
    us8 o;
#pragma unroll
    for (int k = 0; k < 8; ++k) {
        float r = di * (a[k] + b2f(tv[k])) + bb[k];
        if (relu) r = fmaxf(r, 0.f);
        o[k] = f2b(r);
    }
    *(us8*)(S + (size_t)i * HD + col) = o;   // 4 lanes = one full 64B line
}

// ---------------- global mean pool over sorted batch ----------------
__global__ __launch_bounds__(256) void pool2_k(const unsigned short* __restrict__ H2,
                                               const int* __restrict__ batch,
                                               float* __restrict__ sums,
                                               float* __restrict__ cnt) {
    const int t = threadIdx.x;
    const int f = t & 127;
    const int half = t >> 7;
    int i0 = blockIdx.x * 128 + half * 64;
    if (i0 >= N_NODES) return;
    int i1 = i0 + 64; if (i1 > N_NODES) i1 = N_NODES;

    int cur = batch[i0];
    float acc = 0.f;
    float c = 0.f;
    for (int i = i0; i < i1; ++i) {
        int g = batch[i];
        if (g != cur) {
            atomicAdd(&sums[cur * HD + f], acc);
            if (f == 0) atomicAdd(&cnt[cur], c);
            acc = 0.f; c = 0.f; cur = g;
        }
        acc += b2f(H2[(size_t)i * HD + f]);
        c += 1.f;
    }
    atomicAdd(&sums[cur * HD + f], acc);
    if (f == 0) atomicAdd(&cnt[cur], c);
}

// ---------------- head (fp32) ----------------
__global__ __launch_bounds__(512) void head_k(const float* __restrict__ sums,
                                              const float* __restrict__ cnt,
                                              const float* __restrict__ Wh,
                                              const float* __restrict__ bh,
                                              float* __restrict__ out) {
    int t = threadIdx.x;
    int g = t >> 3, o = t & 7;
    float inv = 1.0f / fmaxf(cnt[g], 1.0f);
    float acc = bh[o];
    for (int h = 0; h < HD; ++h)
        acc += sums[g * HD + h] * inv * Wh[h * NOUT + o];
    out[g * NOUT + o] = acc;
}

extern "C" void kernel_launch(void* const* d_in, const int* in_sizes, int n_in,
                              void* d_out, int out_size, void* d_ws, size_t ws_size,
                              hipStream_t stream) {
    const float* x  = (const float*)d_in[0];
    const int*   ei = (const int*)d_in[1];
    const int*   batch = (const int*)d_in[2];
    const float* W0 = (const float*)d_in[3];
    const float* b0 = (const float*)d_in[4];
    const float* W1 = (const float*)d_in[5];
    const float* b1 = (const float*)d_in[6];
    const float* W2 = (const float*)d_in[7];
    const float* b2 = (const float*)d_in[8];
    const float* Wh = (const float*)d_in[9];
    const float* bh = (const float*)d_in[10];
    float* out = (float*)d_out;

    const int* src = ei;
    const int* dst = ei + N_EDGES;

    char* wsb = (char*)d_ws;
    int*            degc  = (int*)(wsb + 0);                     // N ints (200 KB)
    unsigned short* slots = (unsigned short*)(wsb + 200000);     // N*64 ushort (6.4 MB)
    unsigned short* WT    = (unsigned short*)(wsb + 6600000);    // 3*HD*HD bf16 (98 KB)
    unsigned short* A     = (unsigned short*)(wsb + 6698304);    // N*HD bf16 (12.8 MB)
    unsigned short* C     = (unsigned short*)(wsb + 19498304);   // N*HD bf16 (12.8 MB)
    float*          sums  = (float*)(wsb + 32298304);            // G*HD fp32
    float*          cnt   = (float*)(wsb + 32331072);            // G fp32

    const int mmGrid   = (N_NODES + 63) / 64;                    // 782
    const int fillxGrid = ((N_EDGES + EPB - 1) / EPB) * 8;       // 391*8 = 3128
    const int gslGrid  = ((N_NODES + 127) / 128) * 8;            // 391*8 = 3128

    // ---- weight convert + zero-init ----
    cvtw_k<<<(N_NODES + 255) / 256, 256, 0, stream>>>(W0, W1, W2, WT, degc, sums, cnt);

    // ---- XCD-partitioned CSR build ----
    fillx_k<<<fillxGrid, 256, 0, stream>>>(src, dst, degc, slots);

    // ---- layer 0 matmul: x @ W0, *dinv -> A (=T1) ----
    mm_f32in_k<<<mmGrid, 256, 0, stream>>>(x, WT, degc, A);

    // ---- layer 1: sliced gather(T1)+b0+relu -> C (=S1); S1 @ W1 *dinv -> A (=T2) ----
    gslice_k<<<gslGrid, 256, 0, stream>>>(A, degc, slots, b0, C, 1);
    mm_bf_k<<<mmGrid, 256, 0, stream>>>(C, WT + HD * HD, degc, A);

    // ---- layer 2: sliced gather(T2)+b1+relu -> C (=S2); S2 @ W2 *dinv -> A (=T3) ----
    gslice_k<<<gslGrid, 256, 0, stream>>>(A, degc, slots, b1, C, 1);
    mm_bf_k<<<mmGrid, 256, 0, stream>>>(C, WT + 2 * HD * HD, degc, A);

    // ---- layer 3: sliced gather(T3)+b2, no relu -> C (=h3) ----
    gslice_k<<<gslGrid, 256, 0, stream>>>(A, degc, slots, b2, C, 0);

    // ---- pool + head ----
    pool2_k<<<(N_NODES + 127) / 128, 256, 0, stream>>>(C, batch, sums, cnt);
    head_k<<<1, 512, 0, stream>>>(sums, cnt, Wh, bh, out);
}